// Round 1
// baseline (437.202 us; speedup 1.0000x reference)
//
#include <hip/hip_runtime.h>
#include <hip/hip_bf16.h>

#define BB 16
#define SS 2048
#define DD 128

typedef float floatx4 __attribute__((ext_vector_type(4)));
typedef __bf16 bf16x8 __attribute__((ext_vector_type(8)));
typedef unsigned short u16x4 __attribute__((ext_vector_type(4)));

// Column permutation making each MFMA fragment's 8 elements contiguous in LDS.
// Logical d -> storage col c. Fragment (ds, qg) then reads c = 32*ds + 8*qg + j,
// which maps back to d = 32*ds + 4*qg + 16*(j>>2) + (j&3)  == assumed k-slot map.
__device__ __forceinline__ int kcol_perm(int d) {
    return ((d >> 5) << 5) | (((d & 15) >> 2) << 3) | (((d >> 4) & 1) << 2) | (d & 3);
}

__device__ __forceinline__ unsigned short f2bf(float x) {
    __bf16 h = (__bf16)x;
    return __builtin_bit_cast(unsigned short, h);
}

__global__ __launch_bounds__(256, 2)
void attn_scaled_kernel(const float* __restrict__ Q, const float* __restrict__ K,
                        const float* __restrict__ V, const float* __restrict__ Sc,
                        float* __restrict__ Out) {
    // K tile 32x128 as bf16 hi/lo, XOR-swizzled ((row&7)<<4 bytes == <<3 u16).
    __shared__ __align__(16) unsigned short Khi[32 * 128];
    __shared__ __align__(16) unsigned short Klo[32 * 128];
    // V tile transposed [d][kperm], swizzled by ((d&3)<<3) u16.
    __shared__ __align__(16) unsigned short Vt[128 * 32];

    const int t    = threadIdx.x;
    const int w    = t >> 6;
    const int lane = t & 63;
    const int lq   = lane & 15;   // q (as B-col of swapped QK^T) / d-col (PV C)
    const int qg   = lane >> 4;   // quarter-wave id

    // XCD-bijective swizzle: 512 blocks, 8 XCDs -> each XCD owns 2 batches (K/V L2-resident)
    const int p     = blockIdx.x;
    const int wid   = ((p & 7) << 6) + (p >> 3);
    const int batch = wid >> 5;
    const int qt    = wid & 31;
    const int q0    = qt << 6;

    const float* Qb = Q + (size_t)batch * SS * DD;
    const float* Kb = K + (size_t)batch * SS * DD;
    const float* Vb = V + (size_t)batch * SS * DD;

    // ---- Q fragments (hi/lo split), resident in registers -------------------
    const int qrow = q0 + (w << 4) + lq;
    const float* Qr = Qb + (size_t)qrow * DD;
    bf16x8 qh[4], ql[4];
#pragma unroll
    for (int ds = 0; ds < 4; ++ds) {
#pragma unroll
        for (int h = 0; h < 2; ++h) {
            float4 qv = *(const float4*)(Qr + (qg << 2) + (h << 4) + (ds << 5));
            float xs[4] = {qv.x, qv.y, qv.z, qv.w};
#pragma unroll
            for (int e = 0; e < 4; ++e) {
                __bf16 hb = (__bf16)xs[e];
                __bf16 lb = (__bf16)(xs[e] - (float)hb);
                qh[ds][h * 4 + e] = hb;
                ql[ds][h * 4 + e] = lb;
            }
        }
    }

    floatx4 O[8];
#pragma unroll
    for (int i = 0; i < 8; ++i) O[i] = (floatx4){0.f, 0.f, 0.f, 0.f};
    float m_run = -INFINITY;
    float l_run = 0.f;

    const float* ScRow = Sc + (size_t)qrow * SS;

    for (int kt = 0; kt < SS / 32; ++kt) {
        const int kbase = kt << 5;
        __syncthreads();
        // ---- stage K (hi/lo) and V^T tiles into LDS -------------------------
#pragma unroll
        for (int i = 0; i < 4; ++i) {
            int fi  = t + (i << 8);        // float4 index 0..1023
            int row = fi >> 5;             // 0..31
            int c4  = (fi & 31) << 2;      // 0..124
            float4 kv = *(const float4*)(Kb + (size_t)(kbase + row) * DD + c4);
            float4 vv = *(const float4*)(Vb + (size_t)(kbase + row) * DD + c4);
            float ks[4] = {kv.x, kv.y, kv.z, kv.w};
            float vs[4] = {vv.x, vv.y, vv.z, vv.w};
            int cb   = kcol_perm(c4);                       // contiguous for e=0..3
            int widx = (row * 128 + cb) ^ ((row & 7) << 3);
            u16x4 hh, ll;
#pragma unroll
            for (int e = 0; e < 4; ++e) {
                __bf16 hb = (__bf16)ks[e];
                __bf16 lb = (__bf16)(ks[e] - (float)hb);
                hh[e] = __builtin_bit_cast(unsigned short, hb);
                ll[e] = __builtin_bit_cast(unsigned short, lb);
            }
            *(u16x4*)(&Khi[widx]) = hh;
            *(u16x4*)(&Klo[widx]) = ll;
            int kp2 = kcol_perm(row);                        // row < 32
#pragma unroll
            for (int e = 0; e < 4; ++e) {
                int d    = c4 + e;
                int vidx = (d * 32 + kp2) ^ ((d & 3) << 3);
                Vt[vidx] = f2bf(vs[e]);
            }
        }
        __syncthreads();

        // ---- swapped QK^T: S^T[kcol][q], split-bf16 (hh + hl + lh) ----------
        floatx4 st0 = {0.f, 0.f, 0.f, 0.f}, st1 = {0.f, 0.f, 0.f, 0.f};
#pragma unroll
        for (int ds = 0; ds < 4; ++ds) {
            const int r0 = lq, r1 = lq + 16;
            const int col = (ds << 5) + (qg << 3);
            int b0 = (r0 * 128 + col) ^ ((r0 & 7) << 3);
            int b1 = (r1 * 128 + col) ^ ((r1 & 7) << 3);
            bf16x8 kh0 = *(const bf16x8*)(&Khi[b0]);
            bf16x8 kl0 = *(const bf16x8*)(&Klo[b0]);
            bf16x8 kh1 = *(const bf16x8*)(&Khi[b1]);
            bf16x8 kl1 = *(const bf16x8*)(&Klo[b1]);
            st0 = __builtin_amdgcn_mfma_f32_16x16x32_bf16(kh0, qh[ds], st0, 0, 0, 0);
            st1 = __builtin_amdgcn_mfma_f32_16x16x32_bf16(kh1, qh[ds], st1, 0, 0, 0);
            st0 = __builtin_amdgcn_mfma_f32_16x16x32_bf16(kh0, ql[ds], st0, 0, 0, 0);
            st1 = __builtin_amdgcn_mfma_f32_16x16x32_bf16(kh1, ql[ds], st1, 0, 0, 0);
            st0 = __builtin_amdgcn_mfma_f32_16x16x32_bf16(kl0, qh[ds], st0, 0, 0, 0);
            st1 = __builtin_amdgcn_mfma_f32_16x16x32_bf16(kl1, qh[ds], st1, 0, 0, 0);
        }

        // ---- elementwise scale + online softmax -----------------------------
        const float* sr = ScRow + kbase;
        float4 sc0 = *(const float4*)(sr + (qg << 2));
        float4 sc1 = *(const float4*)(sr + 16 + (qg << 2));
        float sv[8];
        sv[0] = st0[0] * sc0.x; sv[1] = st0[1] * sc0.y;
        sv[2] = st0[2] * sc0.z; sv[3] = st0[3] * sc0.w;
        sv[4] = st1[0] * sc1.x; sv[5] = st1[1] * sc1.y;
        sv[6] = st1[2] * sc1.z; sv[7] = st1[3] * sc1.w;

        float tm = fmaxf(fmaxf(fmaxf(sv[0], sv[1]), fmaxf(sv[2], sv[3])),
                         fmaxf(fmaxf(sv[4], sv[5]), fmaxf(sv[6], sv[7])));
        tm = fmaxf(tm, __shfl_xor(tm, 16));
        tm = fmaxf(tm, __shfl_xor(tm, 32));
        float mnew  = fmaxf(m_run, tm);
        float alpha = __expf(m_run - mnew);
        m_run = mnew;

        float psum = 0.f;
        bf16x8 pa;
#pragma unroll
        for (int i = 0; i < 8; ++i) {
            float pe = __expf(sv[i] - mnew);
            psum += pe;
            pa[i] = (__bf16)pe;
        }
        psum += __shfl_xor(psum, 16);
        psum += __shfl_xor(psum, 32);
        l_run = l_run * alpha + psum;

        // rescale O (rows q_local = qg*4+r live on other lanes' alpha)
        float ar0 = __shfl(alpha, (qg << 2) + 0);
        float ar1 = __shfl(alpha, (qg << 2) + 1);
        float ar2 = __shfl(alpha, (qg << 2) + 2);
        float ar3 = __shfl(alpha, (qg << 2) + 3);
#pragma unroll
        for (int df = 0; df < 8; ++df) {
            O[df][0] *= ar0; O[df][1] *= ar1; O[df][2] *= ar2; O[df][3] *= ar3;
        }

        // ---- PV: A = P (direct from S^T accum layout), B = V from LDS -------
#pragma unroll
        for (int df = 0; df < 8; ++df) {
            int d  = lq + (df << 4);
            int vb = (d * 32 + (qg << 3)) ^ ((d & 3) << 3);
            bf16x8 vf = *(const bf16x8*)(&Vt[vb]);
            O[df] = __builtin_amdgcn_mfma_f32_16x16x32_bf16(pa, vf, O[df], 0, 0, 0);
        }
    }

    // ---- epilogue: divide by l, store fp32 ----------------------------------
    float inv0 = 1.f / __shfl(l_run, (qg << 2) + 0);
    float inv1 = 1.f / __shfl(l_run, (qg << 2) + 1);
    float inv2 = 1.f / __shfl(l_run, (qg << 2) + 2);
    float inv3 = 1.f / __shfl(l_run, (qg << 2) + 3);
    const size_t obase = ((size_t)batch * SS + (size_t)(q0 + (w << 4))) * DD;
#pragma unroll
    for (int df = 0; df < 8; ++df) {
        int d = lq + (df << 4);
        Out[obase + (size_t)((qg << 2) + 0) * DD + d] = O[df][0] * inv0;
        Out[obase + (size_t)((qg << 2) + 1) * DD + d] = O[df][1] * inv1;
        Out[obase + (size_t)((qg << 2) + 2) * DD + d] = O[df][2] * inv2;
        Out[obase + (size_t)((qg << 2) + 3) * DD + d] = O[df][3] * inv3;
    }
}

extern "C" void kernel_launch(void* const* d_in, const int* in_sizes, int n_in,
                              void* d_out, int out_size, void* d_ws, size_t ws_size,
                              hipStream_t stream) {
    const float* q  = (const float*)d_in[0];
    const float* k  = (const float*)d_in[1];
    const float* v  = (const float*)d_in[2];
    const float* sc = (const float*)d_in[3];
    float* out = (float*)d_out;
    hipLaunchKernelGGL(attn_scaled_kernel, dim3(512), dim3(256), 0, stream,
                       q, k, v, sc, out);
}

// Round 4
// 230.478 us; speedup vs baseline: 1.8969x; 1.8969x over previous
//
#include <hip/hip_runtime.h>
#include <hip/hip_bf16.h>

#define SS 2048
#define DD 128
#define KT 64
#define NT (SS / KT)

typedef float floatx4 __attribute__((ext_vector_type(4)));
typedef __bf16 bf16x8 __attribute__((ext_vector_type(8)));
typedef unsigned short u16x4 __attribute__((ext_vector_type(4)));
typedef unsigned short u16x8 __attribute__((ext_vector_type(8)));

// Logical d -> storage col for K tiles: fragment (ds,qg) reads 8 contiguous u16
// at 32*ds + 8*qg, mapping back to d = 32ds + 4qg + 16(j>>2) + (j&3) = phi(qg,j).
// Same phi used on both MFMA operands -> any HW k-slot perm cancels
// (HW-verified R1, absmax 0.031).
__device__ __forceinline__ int kcol_perm(int d) {
    return ((d >> 5) << 5) | (((d & 15) >> 2) << 3) | (((d >> 4) & 1) << 2) | (d & 3);
}

__device__ __forceinline__ unsigned short bfbits(float x) {
    __bf16 h = (__bf16)x;
    return __builtin_bit_cast(unsigned short, h);
}

__global__ __launch_bounds__(256, 2)
void attn_scaled_kernel(const float* __restrict__ Q, const float* __restrict__ K,
                        const float* __restrict__ V, const float* __restrict__ Sc,
                        float* __restrict__ Out) {
    // K tile 64x128 bf16 hi/lo, perm cols, XOR-swizzled by ((row&7)<<3) u16.
    __shared__ __align__(16) unsigned short Khi[KT * DD];
    __shared__ __align__(16) unsigned short Klo[KT * DD];
    // V^T tile [d][pos], pos = (kv_half*32 + 8*kgrp + 4h + j) ^ ((d&7)<<3).
    __shared__ __align__(16) unsigned short Vt[DD * KT];

    const int t    = threadIdx.x;
    const int w    = t >> 6;
    const int lane = t & 63;
    const int lq   = lane & 15;   // q column (QK^T C) / d column (PV C)
    const int qg   = lane >> 4;

    // XCD-bijective swizzle: 512 blocks = 8 XCDs x 64; each XCD owns 2 batches.
    const int p     = blockIdx.x;
    const int wid   = ((p & 7) << 6) + (p >> 3);
    const int batch = wid >> 5;
    const int q0    = (wid & 31) << 6;

    const float* Qb = Q + (size_t)batch * SS * DD;
    const float* Kb = K + (size_t)batch * SS * DD;
    const float* Vb = V + (size_t)batch * SS * DD;

    // ---- K staging geometry: thread covers rows srow+8i, cols c4..c4+3 ------
    const int srow = t >> 5;
    const int c4   = (t & 31) << 2;
    const int kw0  = srow * 128 + (kcol_perm(c4) ^ ((srow & 7) << 3));  // +1024*i
    const float* Kp = Kb + (size_t)srow * DD + c4;

    // ---- V staging geometry: thread owns column d, rows by (vkv, task i) -----
    const int vd   = ((w & 1) << 6) + lane;   // d in [0,128)
    const int vkv  = w >> 1;                   // 0/1: key half (32 keys)
    const int vswz = (vd & 7) << 3;
    const float* Vp = Vb + vd;

#define STAGE_K(I, KV) do {                                           \
        float ks_[4] = {(KV).x, (KV).y, (KV).z, (KV).w};              \
        u16x4 hh_, ll_;                                               \
        _Pragma("unroll")                                             \
        for (int e_ = 0; e_ < 4; ++e_) {                              \
            __bf16 hb_ = (__bf16)ks_[e_];                             \
            __bf16 lb_ = (__bf16)(ks_[e_] - (float)hb_);              \
            hh_[e_] = __builtin_bit_cast(unsigned short, hb_);        \
            ll_[e_] = __builtin_bit_cast(unsigned short, lb_);        \
        }                                                             \
        *(u16x4*)&Khi[kw0 + 1024 * (I)] = hh_;                        \
        *(u16x4*)&Klo[kw0 + 1024 * (I)] = ll_;                        \
    } while (0)

    // V task i writes one u16x8: rows 32*vkv + 4*i + 16h + j at column vd,
    // stored at positions (vkv*32 + 8i + 4h + j) ^ vswz of Vt row vd.
#define STAGE_V(I, VPI) do {                                          \
        u16x8 vv_;                                                    \
        _Pragma("unroll")                                             \
        for (int e_ = 0; e_ < 8; ++e_) vv_[e_] = bfbits((VPI)[e_]);   \
        *(u16x8*)&Vt[((vd << 6) + (vkv << 5) + ((I) << 3)) ^ vswz] = vv_; \
    } while (0)

#define LOAD_V(I, VPI, BASE) do {                                     \
        _Pragma("unroll")                                             \
        for (int h_ = 0; h_ < 2; ++h_)                                \
            _Pragma("unroll")                                         \
            for (int j_ = 0; j_ < 4; ++j_)                            \
                (VPI)[h_ * 4 + j_] =                                  \
                    Vp[(BASE) + (size_t)((vkv << 5) + ((I) << 2) + (h_ << 4) + j_) * DD]; \
    } while (0)

    // ---- Q fragments (hi/lo split), register-resident -----------------------
    const int qrow = q0 + (w << 4) + lq;
    const float* Qr = Qb + (size_t)qrow * DD;
    bf16x8 qh[4], ql[4];
#pragma unroll
    for (int ds = 0; ds < 4; ++ds) {
#pragma unroll
        for (int h = 0; h < 2; ++h) {
            float4 qv = *(const float4*)(Qr + (qg << 2) + (h << 4) + (ds << 5));
            float xs[4] = {qv.x, qv.y, qv.z, qv.w};
#pragma unroll
            for (int e = 0; e < 4; ++e) {
                __bf16 hb = (__bf16)xs[e];
                __bf16 lb = (__bf16)(xs[e] - (float)hb);
                qh[ds][h * 4 + e] = hb;
                ql[ds][h * 4 + e] = lb;
            }
        }
    }

    const float* ScRow = Sc + (size_t)qrow * SS;

    // ---- prologue: stage tile 0 --------------------------------------------
    float4 scur0, scur1, scur2, scur3;
    {
        float4 kn[8];
        float  vp[4][8];
#pragma unroll
        for (int i = 0; i < 8; ++i) kn[i] = *(const float4*)(Kp + (size_t)(8 * i) * DD);
#pragma unroll
        for (int i = 0; i < 4; ++i) LOAD_V(i, vp[i], 0);
        scur0 = *(const float4*)(ScRow + 0  + (qg << 2));
        scur1 = *(const float4*)(ScRow + 16 + (qg << 2));
        scur2 = *(const float4*)(ScRow + 32 + (qg << 2));
        scur3 = *(const float4*)(ScRow + 48 + (qg << 2));
#pragma unroll
        for (int i = 0; i < 8; ++i) STAGE_K(i, kn[i]);
#pragma unroll
        for (int i = 0; i < 4; ++i) STAGE_V(i, vp[i]);
    }
    __syncthreads();

    floatx4 O[8];
#pragma unroll
    for (int i = 0; i < 8; ++i) O[i] = (floatx4){0.f, 0.f, 0.f, 0.f};
    float m_run = -INFINITY, l_run = 0.f;

    for (int kt = 0; kt < NT; ++kt) {
        const int kbase = kt << 6;
        const bool pre = (kt + 1 < NT);
        float4 kn[8], scn0, scn1, scn2, scn3;
        float  vp[4][8];
        if (pre) {
            // T14: issue next tile's loads early; LDS-write after the
            // post-compute barrier -> HBM latency hides under compute.
            const size_t off = (size_t)(kbase + KT) * DD;
#pragma unroll
            for (int i = 0; i < 8; ++i)
                kn[i] = *(const float4*)(Kp + off + (size_t)(8 * i) * DD);
#pragma unroll
            for (int i = 0; i < 4; ++i) LOAD_V(i, vp[i], off);
            const float* sr = ScRow + kbase + KT;
            scn0 = *(const float4*)(sr + 0  + (qg << 2));
            scn1 = *(const float4*)(sr + 16 + (qg << 2));
            scn2 = *(const float4*)(sr + 32 + (qg << 2));
            scn3 = *(const float4*)(sr + 48 + (qg << 2));
        }

        // ---- swapped QK^T: S^T tiles, split-bf16 (hh + hl + lh) -------------
        floatx4 st[4];
#pragma unroll
        for (int g = 0; g < 4; ++g) st[g] = (floatx4){0.f, 0.f, 0.f, 0.f};
        const int sx = (lq & 7) << 3;
        __builtin_amdgcn_s_setprio(1);
#pragma unroll
        for (int ds = 0; ds < 4; ++ds) {
            const int cc = (ds << 5) + (qg << 3);
#pragma unroll
            for (int g = 0; g < 4; ++g) {
                const int b = ((g * 16 + lq) * 128 + cc) ^ sx;
                bf16x8 kh = *(const bf16x8*)&Khi[b];
                bf16x8 kl = *(const bf16x8*)&Klo[b];
                st[g] = __builtin_amdgcn_mfma_f32_16x16x32_bf16(kh, qh[ds], st[g], 0, 0, 0);
                st[g] = __builtin_amdgcn_mfma_f32_16x16x32_bf16(kh, ql[ds], st[g], 0, 0, 0);
                st[g] = __builtin_amdgcn_mfma_f32_16x16x32_bf16(kl, qh[ds], st[g], 0, 0, 0);
            }
        }
        __builtin_amdgcn_s_setprio(0);

        // ---- elementwise scale + online softmax -----------------------------
        float sv[16];
        sv[0]  = st[0][0] * scur0.x; sv[1]  = st[0][1] * scur0.y;
        sv[2]  = st[0][2] * scur0.z; sv[3]  = st[0][3] * scur0.w;
        sv[4]  = st[1][0] * scur1.x; sv[5]  = st[1][1] * scur1.y;
        sv[6]  = st[1][2] * scur1.z; sv[7]  = st[1][3] * scur1.w;
        sv[8]  = st[2][0] * scur2.x; sv[9]  = st[2][1] * scur2.y;
        sv[10] = st[2][2] * scur2.z; sv[11] = st[2][3] * scur2.w;
        sv[12] = st[3][0] * scur3.x; sv[13] = st[3][1] * scur3.y;
        sv[14] = st[3][2] * scur3.z; sv[15] = st[3][3] * scur3.w;

        float tm = fmaxf(fmaxf(fmaxf(sv[0], sv[1]), fmaxf(sv[2], sv[3])),
                         fmaxf(fmaxf(sv[4], sv[5]), fmaxf(sv[6], sv[7])));
        float tm2 = fmaxf(fmaxf(fmaxf(sv[8], sv[9]), fmaxf(sv[10], sv[11])),
                          fmaxf(fmaxf(sv[12], sv[13]), fmaxf(sv[14], sv[15])));
        tm = fmaxf(tm, tm2);
        tm = fmaxf(tm, __shfl_xor(tm, 16));
        tm = fmaxf(tm, __shfl_xor(tm, 32));
        float mnew  = fmaxf(m_run, tm);
        float alpha = __expf(m_run - mnew);
        m_run = mnew;

        float psum = 0.f;
        bf16x8 pa0, pa1;
#pragma unroll
        for (int e = 0; e < 4; ++e) {
            float p0 = __expf(sv[e]      - mnew);
            float p1 = __expf(sv[4 + e]  - mnew);
            float p2 = __expf(sv[8 + e]  - mnew);
            float p3 = __expf(sv[12 + e] - mnew);
            psum += (p0 + p1) + (p2 + p3);
            pa0[e] = (__bf16)p0; pa0[4 + e] = (__bf16)p1;
            pa1[e] = (__bf16)p2; pa1[4 + e] = (__bf16)p3;
        }
        psum += __shfl_xor(psum, 16);
        psum += __shfl_xor(psum, 32);
        l_run = l_run * alpha + psum;

        float ar0 = __shfl(alpha, (qg << 2) + 0);
        float ar1 = __shfl(alpha, (qg << 2) + 1);
        float ar2 = __shfl(alpha, (qg << 2) + 2);
        float ar3 = __shfl(alpha, (qg << 2) + 3);
#pragma unroll
        for (int df = 0; df < 8; ++df) {
            O[df][0] *= ar0; O[df][1] *= ar1; O[df][2] *= ar2; O[df][3] *= ar3;
        }

        // ---- PV: A = P (from S^T accum layout), B = V^T b128 ----------------
        // R3 BUG FIX: k-half bit (32) must be inside the XOR. sx occupies
        // bits 3..5; vb+32 carried into bit 6 (next d row) when d&4 != 0.
        __builtin_amdgcn_s_setprio(1);
#pragma unroll
        for (int df = 0; df < 8; ++df) {
            const int d   = lq + (df << 4);
            const int vb0 = (((d << 6) +      (qg << 3)) ^ sx);  // d&7 == lq&7
            const int vb1 = (((d << 6) + 32 + (qg << 3)) ^ sx);
            bf16x8 vf0 = *(const bf16x8*)&Vt[vb0];
            bf16x8 vf1 = *(const bf16x8*)&Vt[vb1];
            O[df] = __builtin_amdgcn_mfma_f32_16x16x32_bf16(pa0, vf0, O[df], 0, 0, 0);
            O[df] = __builtin_amdgcn_mfma_f32_16x16x32_bf16(pa1, vf1, O[df], 0, 0, 0);
        }
        __builtin_amdgcn_s_setprio(0);

        if (pre) {
            __syncthreads();   // all waves done reading LDS tile kt
#pragma unroll
            for (int i = 0; i < 8; ++i) STAGE_K(i, kn[i]);
#pragma unroll
            for (int i = 0; i < 4; ++i) STAGE_V(i, vp[i]);
            scur0 = scn0; scur1 = scn1; scur2 = scn2; scur3 = scn3;
            __syncthreads();   // tile kt+1 visible
        }
    }

    // ---- epilogue -----------------------------------------------------------
    float inv0 = 1.f / __shfl(l_run, (qg << 2) + 0);
    float inv1 = 1.f / __shfl(l_run, (qg << 2) + 1);
    float inv2 = 1.f / __shfl(l_run, (qg << 2) + 2);
    float inv3 = 1.f / __shfl(l_run, (qg << 2) + 3);
    const size_t obase = ((size_t)batch * SS + (size_t)(q0 + (w << 4))) * DD;
#pragma unroll
    for (int df = 0; df < 8; ++df) {
        int d = lq + (df << 4);
        Out[obase + (size_t)((qg << 2) + 0) * DD + d] = O[df][0] * inv0;
        Out[obase + (size_t)((qg << 2) + 1) * DD + d] = O[df][1] * inv1;
        Out[obase + (size_t)((qg << 2) + 2) * DD + d] = O[df][2] * inv2;
        Out[obase + (size_t)((qg << 2) + 3) * DD + d] = O[df][3] * inv3;
    }
#undef STAGE_K
#undef STAGE_V
#undef LOAD_V
}

extern "C" void kernel_launch(void* const* d_in, const int* in_sizes, int n_in,
                              void* d_out, int out_size, void* d_ws, size_t ws_size,
                              hipStream_t stream) {
    const float* q  = (const float*)d_in[0];
    const float* k  = (const float*)d_in[1];
    const float* v  = (const float*)d_in[2];
    const float* sc = (const float*)d_in[3];
    float* out = (float*)d_out;
    hipLaunchKernelGGL(attn_scaled_kernel, dim3(512), dim3(256), 0, stream,
                       q, k, v, sc, out);
}

// Round 5
// 227.668 us; speedup vs baseline: 1.9203x; 1.0123x over previous
//
#include <hip/hip_runtime.h>
#include <hip/hip_bf16.h>

#define SS 2048
#define DD 128
#define KT 64
#define NT (SS / KT)

typedef float floatx4 __attribute__((ext_vector_type(4)));
typedef __bf16 bf16x8 __attribute__((ext_vector_type(8)));
typedef unsigned short u16x4 __attribute__((ext_vector_type(4)));
typedef unsigned short u16x8 __attribute__((ext_vector_type(8)));

// Logical d -> storage col for K tiles: fragment (ds,qg) reads 8 contiguous u16
// at 32*ds + 8*qg, mapping back to d = 32ds + 4qg + 16(j>>2) + (j&3) = phi(qg,j).
// Same phi used on both MFMA operands -> any HW k-slot perm cancels
// (HW-verified R1/R4, absmax 0.031).
__device__ __forceinline__ int kcol_perm(int d) {
    return ((d >> 5) << 5) | (((d & 15) >> 2) << 3) | (((d >> 4) & 1) << 2) | (d & 3);
}

__device__ __forceinline__ unsigned short bfbits(float x) {
    __bf16 h = (__bf16)x;
    return __builtin_bit_cast(unsigned short, h);
}

// R5: 256 blocks x 4 waves; each wave owns 32 q-rows (2 halves of 16).
// K/V LDS fragments are read ONCE and feed MFMAs for BOTH halves ->
// per-CU LDS read traffic halves vs R4 (384->192 KB/tile), which was ~50%
// of R4's cycle budget. 1 block/CU, 1 wave/SIMD; launch_bounds(256,1)
// lifts the VGPR cap to 512 so the ~320-reg peak cannot spill.
__global__ __launch_bounds__(256, 1)
void attn_scaled_kernel(const float* __restrict__ Q, const float* __restrict__ K,
                        const float* __restrict__ V, const float* __restrict__ Sc,
                        float* __restrict__ Out) {
    // K tile 64x128 bf16 hi/lo, perm cols, XOR-swizzled by ((row&7)<<3) u16.
    __shared__ __align__(16) unsigned short Khi[KT * DD];
    __shared__ __align__(16) unsigned short Klo[KT * DD];
    // V^T tile [d][pos], pos = (kv_half*32 + 8*kgrp + 4h + j) ^ ((d&7)<<3).
    __shared__ __align__(16) unsigned short Vt[DD * KT];

    const int t    = threadIdx.x;
    const int w    = t >> 6;
    const int lane = t & 63;
    const int lq   = lane & 15;   // q column (QK^T C) / d column (PV C)
    const int qg   = lane >> 4;

    // XCD-bijective swizzle: 256 blocks = 8 XCDs x 32; each XCD owns 2 batches
    // (K/V 4 MB = L2-resident per XCD).
    const int p     = blockIdx.x;
    const int wid   = ((p & 7) << 5) + (p >> 3);
    const int batch = wid >> 4;
    const int q0    = (wid & 15) << 7;   // 128 q-rows per block

    const float* Qb = Q + (size_t)batch * SS * DD;
    const float* Kb = K + (size_t)batch * SS * DD;
    const float* Vb = V + (size_t)batch * SS * DD;

    // ---- K staging geometry: thread covers rows srow+8i, cols c4..c4+3 ------
    const int srow = t >> 5;
    const int c4   = (t & 31) << 2;
    const int kw0  = srow * 128 + (kcol_perm(c4) ^ ((srow & 7) << 3));  // +1024*i
    const float* Kp = Kb + (size_t)srow * DD + c4;

    // ---- V staging geometry: thread owns column d, rows by (vkv, task i) -----
    const int vd   = ((w & 1) << 6) + lane;   // d in [0,128)
    const int vkv  = w >> 1;                   // 0/1: key half (32 keys)
    const int vswz = (vd & 7) << 3;
    const float* Vp = Vb + vd;

#define STAGE_K(I, KV) do {                                           \
        float ks_[4] = {(KV).x, (KV).y, (KV).z, (KV).w};              \
        u16x4 hh_, ll_;                                               \
        _Pragma("unroll")                                             \
        for (int e_ = 0; e_ < 4; ++e_) {                              \
            __bf16 hb_ = (__bf16)ks_[e_];                             \
            __bf16 lb_ = (__bf16)(ks_[e_] - (float)hb_);              \
            hh_[e_] = __builtin_bit_cast(unsigned short, hb_);        \
            ll_[e_] = __builtin_bit_cast(unsigned short, lb_);        \
        }                                                             \
        *(u16x4*)&Khi[kw0 + 1024 * (I)] = hh_;                        \
        *(u16x4*)&Klo[kw0 + 1024 * (I)] = ll_;                        \
    } while (0)

    // V task i writes one u16x8: rows 32*vkv + 4*i + 16h + j at column vd,
    // stored at positions (vkv*32 + 8i + 4h + j) ^ vswz of Vt row vd.
#define STAGE_V(I, VPI) do {                                          \
        u16x8 vv_;                                                    \
        _Pragma("unroll")                                             \
        for (int e_ = 0; e_ < 8; ++e_) vv_[e_] = bfbits((VPI)[e_]);   \
        *(u16x8*)&Vt[((vd << 6) + (vkv << 5) + ((I) << 3)) ^ vswz] = vv_; \
    } while (0)

#define LOAD_V(I, VPI, BASE) do {                                     \
        _Pragma("unroll")                                             \
        for (int h_ = 0; h_ < 2; ++h_)                                \
            _Pragma("unroll")                                         \
            for (int j_ = 0; j_ < 4; ++j_)                            \
                (VPI)[h_ * 4 + j_] =                                  \
                    Vp[(BASE) + (size_t)((vkv << 5) + ((I) << 2) + (h_ << 4) + j_) * DD]; \
    } while (0)

    // ---- Q fragments (hi/lo split), 2 halves of 16 q, register-resident -----
    const int qrow0 = q0 + (w << 5) + lq;          // half 0; half 1 = +16
    bf16x8 qh[2][4], ql[2][4];
#pragma unroll
    for (int h2 = 0; h2 < 2; ++h2) {
        const float* Qr = Qb + (size_t)(qrow0 + 16 * h2) * DD;
#pragma unroll
        for (int ds = 0; ds < 4; ++ds) {
#pragma unroll
            for (int h = 0; h < 2; ++h) {
                float4 qv = *(const float4*)(Qr + (qg << 2) + (h << 4) + (ds << 5));
                float xs[4] = {qv.x, qv.y, qv.z, qv.w};
#pragma unroll
                for (int e = 0; e < 4; ++e) {
                    __bf16 hb = (__bf16)xs[e];
                    __bf16 lb = (__bf16)(xs[e] - (float)hb);
                    qh[h2][ds][h * 4 + e] = hb;
                    ql[h2][ds][h * 4 + e] = lb;
                }
            }
        }
    }

    const float* ScRow0 = Sc + (size_t)qrow0 * SS;   // half 1 = +16*SS

    // ---- prologue: stage tile 0 --------------------------------------------
    float4 scur[2][4];
    {
        float4 kn[8];
        float  vp[4][8];
#pragma unroll
        for (int i = 0; i < 8; ++i) kn[i] = *(const float4*)(Kp + (size_t)(8 * i) * DD);
#pragma unroll
        for (int i = 0; i < 4; ++i) LOAD_V(i, vp[i], 0);
#pragma unroll
        for (int h2 = 0; h2 < 2; ++h2)
#pragma unroll
            for (int g = 0; g < 4; ++g)
                scur[h2][g] = *(const float4*)(ScRow0 + (size_t)(h2 * 16) * SS + g * 16 + (qg << 2));
#pragma unroll
        for (int i = 0; i < 8; ++i) STAGE_K(i, kn[i]);
#pragma unroll
        for (int i = 0; i < 4; ++i) STAGE_V(i, vp[i]);
    }
    __syncthreads();

    floatx4 O[2][8];
#pragma unroll
    for (int h2 = 0; h2 < 2; ++h2)
#pragma unroll
        for (int i = 0; i < 8; ++i) O[h2][i] = (floatx4){0.f, 0.f, 0.f, 0.f};
    float m_run[2] = {-INFINITY, -INFINITY};
    float l_run[2] = {0.f, 0.f};

    for (int kt = 0; kt < NT; ++kt) {
        const int kbase = kt << 6;
        const bool pre = (kt + 1 < NT);
        float4 kn[8], scn[2][4];
        float  vp[4][8];
        if (pre) {
            // T14: issue next tile's loads early; LDS-write after the
            // post-compute barrier -> HBM latency hides under compute.
            const size_t off = (size_t)(kbase + KT) * DD;
#pragma unroll
            for (int i = 0; i < 8; ++i)
                kn[i] = *(const float4*)(Kp + off + (size_t)(8 * i) * DD);
#pragma unroll
            for (int i = 0; i < 4; ++i) LOAD_V(i, vp[i], off);
#pragma unroll
            for (int h2 = 0; h2 < 2; ++h2)
#pragma unroll
                for (int g = 0; g < 4; ++g)
                    scn[h2][g] = *(const float4*)(ScRow0 + (size_t)(h2 * 16) * SS
                                                  + kbase + KT + g * 16 + (qg << 2));
        }

        // ---- swapped QK^T: S^T tiles, split-bf16 (hh + hl + lh) -------------
        // K fragments read ONCE, feed both q-halves (A-reuse x2).
        floatx4 st[2][4];
#pragma unroll
        for (int h2 = 0; h2 < 2; ++h2)
#pragma unroll
            for (int g = 0; g < 4; ++g) st[h2][g] = (floatx4){0.f, 0.f, 0.f, 0.f};
        const int sx = (lq & 7) << 3;
        __builtin_amdgcn_s_setprio(1);
#pragma unroll
        for (int ds = 0; ds < 4; ++ds) {
            const int cc = (ds << 5) + (qg << 3);
#pragma unroll
            for (int g = 0; g < 4; ++g) {
                const int b = ((g * 16 + lq) * 128 + cc) ^ sx;
                bf16x8 kh = *(const bf16x8*)&Khi[b];
                bf16x8 kl = *(const bf16x8*)&Klo[b];
#pragma unroll
                for (int h2 = 0; h2 < 2; ++h2) {
                    st[h2][g] = __builtin_amdgcn_mfma_f32_16x16x32_bf16(kh, qh[h2][ds], st[h2][g], 0, 0, 0);
                    st[h2][g] = __builtin_amdgcn_mfma_f32_16x16x32_bf16(kh, ql[h2][ds], st[h2][g], 0, 0, 0);
                    st[h2][g] = __builtin_amdgcn_mfma_f32_16x16x32_bf16(kl, qh[h2][ds], st[h2][g], 0, 0, 0);
                }
            }
        }
        __builtin_amdgcn_s_setprio(0);

        // ---- elementwise scale + online softmax (per half) ------------------
        bf16x8 pa[2][2];
#pragma unroll
        for (int h2 = 0; h2 < 2; ++h2) {
            float sv[16];
#pragma unroll
            for (int g = 0; g < 4; ++g) {
                sv[g * 4 + 0] = st[h2][g][0] * scur[h2][g].x;
                sv[g * 4 + 1] = st[h2][g][1] * scur[h2][g].y;
                sv[g * 4 + 2] = st[h2][g][2] * scur[h2][g].z;
                sv[g * 4 + 3] = st[h2][g][3] * scur[h2][g].w;
            }
            float tm = fmaxf(fmaxf(fmaxf(sv[0], sv[1]), fmaxf(sv[2], sv[3])),
                             fmaxf(fmaxf(sv[4], sv[5]), fmaxf(sv[6], sv[7])));
            float tm2 = fmaxf(fmaxf(fmaxf(sv[8], sv[9]), fmaxf(sv[10], sv[11])),
                              fmaxf(fmaxf(sv[12], sv[13]), fmaxf(sv[14], sv[15])));
            tm = fmaxf(tm, tm2);
            tm = fmaxf(tm, __shfl_xor(tm, 16));
            tm = fmaxf(tm, __shfl_xor(tm, 32));
            float mnew  = fmaxf(m_run[h2], tm);
            float alpha = __expf(m_run[h2] - mnew);
            m_run[h2] = mnew;

            float psum = 0.f;
#pragma unroll
            for (int e = 0; e < 4; ++e) {
                float p0 = __expf(sv[e]      - mnew);
                float p1 = __expf(sv[4 + e]  - mnew);
                float p2 = __expf(sv[8 + e]  - mnew);
                float p3 = __expf(sv[12 + e] - mnew);
                psum += (p0 + p1) + (p2 + p3);
                pa[h2][0][e] = (__bf16)p0; pa[h2][0][4 + e] = (__bf16)p1;
                pa[h2][1][e] = (__bf16)p2; pa[h2][1][4 + e] = (__bf16)p3;
            }
            psum += __shfl_xor(psum, 16);
            psum += __shfl_xor(psum, 32);
            l_run[h2] = l_run[h2] * alpha + psum;

            float ar0 = __shfl(alpha, (qg << 2) + 0);
            float ar1 = __shfl(alpha, (qg << 2) + 1);
            float ar2 = __shfl(alpha, (qg << 2) + 2);
            float ar3 = __shfl(alpha, (qg << 2) + 3);
#pragma unroll
            for (int df = 0; df < 8; ++df) {
                O[h2][df][0] *= ar0; O[h2][df][1] *= ar1;
                O[h2][df][2] *= ar2; O[h2][df][3] *= ar3;
            }
        }

        // ---- PV: A = P (from S^T accum layout), B = V^T b128 ----------------
        // V fragments read ONCE, feed both halves. k-half bit inside the XOR
        // (R4 fix).
        __builtin_amdgcn_s_setprio(1);
#pragma unroll
        for (int df = 0; df < 8; ++df) {
            const int d   = lq + (df << 4);
            const int vb0 = (((d << 6) +      (qg << 3)) ^ sx);  // d&7 == lq&7
            const int vb1 = (((d << 6) + 32 + (qg << 3)) ^ sx);
            bf16x8 vf0 = *(const bf16x8*)&Vt[vb0];
            bf16x8 vf1 = *(const bf16x8*)&Vt[vb1];
#pragma unroll
            for (int h2 = 0; h2 < 2; ++h2) {
                O[h2][df] = __builtin_amdgcn_mfma_f32_16x16x32_bf16(pa[h2][0], vf0, O[h2][df], 0, 0, 0);
                O[h2][df] = __builtin_amdgcn_mfma_f32_16x16x32_bf16(pa[h2][1], vf1, O[h2][df], 0, 0, 0);
            }
        }
        __builtin_amdgcn_s_setprio(0);

        if (pre) {
            __syncthreads();   // all waves done reading LDS tile kt
#pragma unroll
            for (int i = 0; i < 8; ++i) STAGE_K(i, kn[i]);
#pragma unroll
            for (int i = 0; i < 4; ++i) STAGE_V(i, vp[i]);
#pragma unroll
            for (int h2 = 0; h2 < 2; ++h2)
#pragma unroll
                for (int g = 0; g < 4; ++g) scur[h2][g] = scn[h2][g];
            __syncthreads();   // tile kt+1 visible
        }
    }

    // ---- epilogue -----------------------------------------------------------
#pragma unroll
    for (int h2 = 0; h2 < 2; ++h2) {
        float inv0 = 1.f / __shfl(l_run[h2], (qg << 2) + 0);
        float inv1 = 1.f / __shfl(l_run[h2], (qg << 2) + 1);
        float inv2 = 1.f / __shfl(l_run[h2], (qg << 2) + 2);
        float inv3 = 1.f / __shfl(l_run[h2], (qg << 2) + 3);
        const size_t obase = ((size_t)batch * SS + (size_t)(q0 + (w << 5) + 16 * h2)) * DD;
#pragma unroll
        for (int df = 0; df < 8; ++df) {
            int d = lq + (df << 4);
            Out[obase + (size_t)((qg << 2) + 0) * DD + d] = O[h2][df][0] * inv0;
            Out[obase + (size_t)((qg << 2) + 1) * DD + d] = O[h2][df][1] * inv1;
            Out[obase + (size_t)((qg << 2) + 2) * DD + d] = O[h2][df][2] * inv2;
            Out[obase + (size_t)((qg << 2) + 3) * DD + d] = O[h2][df][3] * inv3;
        }
    }
#undef STAGE_K
#undef STAGE_V
#undef LOAD_V
}

extern "C" void kernel_launch(void* const* d_in, const int* in_sizes, int n_in,
                              void* d_out, int out_size, void* d_ws, size_t ws_size,
                              hipStream_t stream) {
    const float* q  = (const float*)d_in[0];
    const float* k  = (const float*)d_in[1];
    const float* v  = (const float*)d_in[2];
    const float* sc = (const float*)d_in[3];
    float* out = (float*)d_out;
    hipLaunchKernelGGL(attn_scaled_kernel, dim3(256), dim3(256), 0, stream,
                       q, k, v, sc, out);
}